// Round 1
// baseline (6046.465 us; speedup 1.0000x reference)
//
#include <hip/hip_runtime.h>
#include <hip/hip_fp16.h>

// Problem: 4-layer 5-point-cross-stencil CNN, NCHW fp32.
//   x[8,6,256,256] -> conv(w1[128,6,5])+relu -> conv(w2[128,128,5])+relu
//                  -> conv(w3[128,128,5])+relu -> conv(w4[6,128,5]) -> out
// Tap order in w[oc,ic,5]: 0=center 1=up(i-1) 2=down(i+1) 3=left(j-1) 4=right(j+1)
// (jax conv is correlation, no flip).
//
// Round-1 baseline: fp32 VALU compute, fp16 intermediate activations in d_ws
// (2 x 8*128*256*256 half = 268 MB). One block = one image row (256 threads),
// OCPB output channels per block; weight/bias indices are wave-uniform so the
// compiler scalarizes them to s_load.

#define BB   8
#define HH   256
#define WW   256
#define INC  6
#define HIDC 128
#define OUTC 6

__device__ __forceinline__ float to_f(float v)  { return v; }
__device__ __forceinline__ float to_f(__half v) { return __half2float(v); }
__device__ __forceinline__ void  from_f(float&  o, float v) { o = v; }
__device__ __forceinline__ void  from_f(__half& o, float v) { o = __float2half(v); }

template<int IC, int OCPB, bool RELU, typename TIN, typename TOUT>
__global__ __launch_bounds__(256) void cross_layer(
    const TIN* __restrict__ x, const float* __restrict__ w,
    const float* __restrict__ bias, TOUT* __restrict__ y, int OC)
{
    const int j   = threadIdx.x;          // 0..255 = W
    const int i   = blockIdx.x;           // row
    const int b   = blockIdx.y;           // batch
    const int ocg = blockIdx.z * OCPB;    // first oc of this block

    float acc[OCPB];
#pragma unroll
    for (int k = 0; k < OCPB; ++k) acc[k] = bias[ocg + k];

    const bool has_u = (i > 0), has_d = (i < HH - 1);
    const bool has_l = (j > 0), has_r = (j < WW - 1);

    for (int ic = 0; ic < IC; ++ic) {
        const TIN* xp = x + (((size_t)b * IC + ic) * HH + i) * WW;
        const float c = to_f(xp[j]);
        const float u = has_u ? to_f(xp[j - WW]) : 0.f;
        const float d = has_d ? to_f(xp[j + WW]) : 0.f;
        const float l = has_l ? to_f(xp[j - 1])  : 0.f;
        const float r = has_r ? to_f(xp[j + 1])  : 0.f;
        const float* wp = w + ((size_t)ocg * IC + ic) * 5;
#pragma unroll
        for (int k = 0; k < OCPB; ++k) {
            const float* wk = wp + (size_t)k * IC * 5;   // wave-uniform -> s_load
            acc[k] += wk[0] * c + wk[1] * u + wk[2] * d + wk[3] * l + wk[4] * r;
        }
    }

    TOUT* yp = y + (((size_t)b * OC + ocg) * HH + i) * WW + j;
#pragma unroll
    for (int k = 0; k < OCPB; ++k) {
        float v = acc[k];
        if (RELU) v = fmaxf(v, 0.f);
        from_f(yp[(size_t)k * HH * WW], v);
    }
}

extern "C" void kernel_launch(void* const* d_in, const int* in_sizes, int n_in,
                              void* d_out, int out_size, void* d_ws, size_t ws_size,
                              hipStream_t stream) {
    const float* x  = (const float*)d_in[0];
    const float* w1 = (const float*)d_in[1];
    const float* b1 = (const float*)d_in[2];
    const float* w2 = (const float*)d_in[3];
    const float* b2 = (const float*)d_in[4];
    const float* w3 = (const float*)d_in[5];
    const float* b3 = (const float*)d_in[6];
    const float* w4 = (const float*)d_in[7];
    const float* b4 = (const float*)d_in[8];
    float* out = (float*)d_out;

    // Workspace: two ping-pong fp16 activation buffers, 134 MB each.
    const size_t act_elems = (size_t)BB * HIDC * HH * WW;   // 8*128*256*256
    __half* hA = (__half*)d_ws;
    __half* hB = hA + act_elems;                            // needs 268 MB total ws

    dim3 blk(256, 1, 1);

    // L1: x(fp32, ic=6) -> hA (relu)
    cross_layer<INC, 8, true, float, __half>
        <<<dim3(HH, BB, HIDC / 8), blk, 0, stream>>>(x, w1, b1, hA, HIDC);
    // L2: hA -> hB (relu)
    cross_layer<HIDC, 8, true, __half, __half>
        <<<dim3(HH, BB, HIDC / 8), blk, 0, stream>>>(hA, w2, b2, hB, HIDC);
    // L3: hB -> hA (relu)
    cross_layer<HIDC, 8, true, __half, __half>
        <<<dim3(HH, BB, HIDC / 8), blk, 0, stream>>>(hB, w3, b3, hA, HIDC);
    // L4: hA -> out (fp32, oc=6, no relu)
    cross_layer<HIDC, 6, false, __half, float>
        <<<dim3(HH, BB, 1), blk, 0, stream>>>(hA, w4, b4, out, OUTC);
}

// Round 3
// 613.560 us; speedup vs baseline: 9.8547x; 9.8547x over previous
//
#include <hip/hip_runtime.h>

// 4-layer 5-point cross-stencil CNN on MI355X.
// Strategy: implicit GEMM on matrix cores.
//   M = pixels (8*256*256), N = oc, K = tap*ic (5 taps).
// Intermediates NHWC fp16 in d_ws (exactly 256 MiB); transposed weights
// Wt[tap][oc][ic] fp16 live in __device__ globals (340 KB) because
// ws_size is exactly 2x134 MB (round-2 lesson: +348 KB tripped the guard).
// Middle layers: WG = 4 rows x 16 px x 128 oc; A-panel in LDS filled ONCE
// (no per-kstep barriers); B-frags from L2-resident Wt via global loads.
// mfma_f32_16x16x32_f16: A[m=lane&15][k=quad*8+j], B[n=lane&15][k=quad*8+j],
// C/D: col(n)=lane&15, row(m)=quad*4+reg.   Tap order: c,u,d,l,r.

#define BB   8
#define HH   256
#define WW   256
#define HIDC 128

typedef _Float16 f16x8 __attribute__((ext_vector_type(8)));
typedef float    f32x4 __attribute__((ext_vector_type(4)));

// Transposed fp16 weight tables (rewritten every kernel_launch by prep).
__device__ _Float16 W2g[5 * 128 * 128];   // [tap][oc][ic]
__device__ _Float16 W3g[5 * 128 * 128];
__device__ _Float16 W4g[5 * 16 * 128];    // oc padded 6 -> 16

// ---------------- weight prep: w[oc][ic][5] fp32 -> Wt[tap][oc][ic] fp16 ----
__global__ void prep(const float* __restrict__ w2, const float* __restrict__ w3,
                     const float* __restrict__ w4)
{
    int idx = blockIdx.x * 256 + threadIdx.x;
    if (idx < 81920) {                       // Wt2: [5][128][128]
        int t = idx / 16384, rem = idx % 16384, oc = rem >> 7, ic = rem & 127;
        W2g[idx] = (_Float16)w2[(oc * 128 + ic) * 5 + t];
    } else if (idx < 163840) {               // Wt3
        int k = idx - 81920;
        int t = k / 16384, rem = k % 16384, oc = rem >> 7, ic = rem & 127;
        W3g[k] = (_Float16)w3[(oc * 128 + ic) * 5 + t];
    } else if (idx < 174080) {               // Wt4: [5][16(pad)][128]
        int k = idx - 163840;
        int t = k / 2048, rem = k % 2048, oc = rem >> 7, ic = rem & 127;
        W4g[k] = (_Float16)((oc < 6) ? w4[(oc * 128 + ic) * 5 + t] : 0.f);
    }
}

// ---------------- L1: IC=6 -> 128, VALU, NCHW fp32 in -> NHWC fp16 out ------
__global__ __launch_bounds__(256, 4) void l1_kernel(
    const float* __restrict__ x, const float* __restrict__ w1,
    const float* __restrict__ b1, _Float16* __restrict__ a1)
{
    int px = blockIdx.x * 256 + threadIdx.x;
    int b = px >> 16, ij = px & 65535, i = ij >> 8, j = ij & 255;
    const int di[5] = {0, -1, 1, 0, 0}, dj[5] = {0, 0, 0, -1, 1};
    float xin[30];
#pragma unroll
    for (int t = 0; t < 5; ++t) {
        int gi = i + di[t], gj = j + dj[t];
        bool ok = ((unsigned)gi < 256u) && ((unsigned)gj < 256u);
#pragma unroll
        for (int ic = 0; ic < 6; ++ic)
            xin[t * 6 + ic] = ok ? x[(((size_t)b * 6 + ic) * 256 + gi) * 256 + gj] : 0.f;
    }
#pragma unroll
    for (int c = 0; c < 8; ++c) {            // 8 chunks of 16 oc
        float acc[16];
#pragma unroll
        for (int u = 0; u < 16; ++u) {
            int oc = c * 16 + u;
            float a = b1[oc];                // wave-uniform -> s_load
#pragma unroll
            for (int ic = 0; ic < 6; ++ic)
#pragma unroll
                for (int t = 0; t < 5; ++t)
                    a += w1[oc * 30 + ic * 5 + t] * xin[t * 6 + ic];
            acc[u] = fmaxf(a, 0.f);
        }
        f16x8 v0, v1;
#pragma unroll
        for (int e = 0; e < 8; ++e) { v0[e] = (_Float16)acc[e]; v1[e] = (_Float16)acc[8 + e]; }
        *(f16x8*)&a1[(size_t)px * 128 + c * 16]     = v0;
        *(f16x8*)&a1[(size_t)px * 128 + c * 16 + 8] = v1;
    }
}

// ---------------- middle layers: NHWC fp16 -> NHWC fp16, MFMA ---------------
// WG: 4 rows x 16 px (M=64), N=128. A-panel LDS: 6 rows x 18 px x 136 (pad).
// LAYER selects the __device__ weight table (host can't take symbol addrs
// without a runtime call, so resolve it in device code).
template<int LAYER>
__global__ __launch_bounds__(256, 3) void gmid(
    const _Float16* __restrict__ in, const float* __restrict__ bias,
    _Float16* __restrict__ outp)
{
    const _Float16* wt = (LAYER == 2) ? W2g : W3g;
    __shared__ _Float16 Al[6 * 18 * 136];
    const int tid = threadIdx.x;
    const int jt = blockIdx.x, it = blockIdx.y, b = blockIdx.z;
    const int i0 = it * 4, j0 = jt * 16;

    for (int t = tid; t < 6 * 18 * 16; t += 256) {
        int r = t / 288, rem = t % 288, p = rem >> 4, q = rem & 15;
        int gi = i0 - 1 + r, gj = j0 - 1 + p;
        f16x8 v = {0, 0, 0, 0, 0, 0, 0, 0};
        if (((unsigned)gi < 256u) && ((unsigned)gj < 256u))
            v = *(const f16x8*)&in[(((size_t)b * 256 + gi) * 256 + gj) * 128 + q * 8];
        *(f16x8*)&Al[(r * 18 + p) * 136 + q * 8] = v;
    }
    __syncthreads();

    const int lane = tid & 63, wid = tid >> 6;
    const int l16 = lane & 15, quad = lane >> 4;
    const int n0 = wid * 32;
    f32x4 acc[4][2] = {};
    const int DR[5] = {1, 0, 2, 1, 1}, DP[5] = {1, 1, 1, 0, 2};

#pragma unroll
    for (int ks = 0; ks < 20; ++ks) {
        const int tap = ks >> 2, kc = ks & 3;
        const int koff = kc * 32 + quad * 8;
        f16x8 bf0 = *(const f16x8*)&wt[(size_t)(tap * 128 + n0 + l16) * 128 + koff];
        f16x8 bf1 = *(const f16x8*)&wt[(size_t)(tap * 128 + n0 + 16 + l16) * 128 + koff];
        const int pb = DP[tap] + l16, rb = DR[tap];
#pragma unroll
        for (int mt = 0; mt < 4; ++mt) {
            f16x8 af = *(const f16x8*)&Al[((rb + mt) * 18 + pb) * 136 + koff];
            acc[mt][0] = __builtin_amdgcn_mfma_f32_16x16x32_f16(af, bf0, acc[mt][0], 0, 0, 0);
            acc[mt][1] = __builtin_amdgcn_mfma_f32_16x16x32_f16(af, bf1, acc[mt][1], 0, 0, 0);
        }
    }

    const float bv0 = bias[n0 + l16], bv1 = bias[n0 + 16 + l16];
#pragma unroll
    for (int mt = 0; mt < 4; ++mt) {
        const size_t rowb = ((size_t)b * 256 + i0 + mt) * 256 + j0;
#pragma unroll
        for (int vi = 0; vi < 4; ++vi) {
            const size_t pxb = (rowb + quad * 4 + vi) * 128;
            outp[pxb + n0 + l16]      = (_Float16)fmaxf(acc[mt][0][vi] + bv0, 0.f);
            outp[pxb + n0 + 16 + l16] = (_Float16)fmaxf(acc[mt][1][vi] + bv1, 0.f);
        }
    }
}

// ---------------- L4: 128 -> 6 (padded 16), MFMA, fp32 NCHW out -------------
__global__ __launch_bounds__(256, 3) void g4(
    const _Float16* __restrict__ in, const float* __restrict__ bias,
    float* __restrict__ outp)
{
    __shared__ _Float16 Al[6 * 18 * 136];
    const int tid = threadIdx.x;
    const int jt = blockIdx.x, it = blockIdx.y, b = blockIdx.z;
    const int i0 = it * 4, j0 = jt * 16;

    for (int t = tid; t < 6 * 18 * 16; t += 256) {
        int r = t / 288, rem = t % 288, p = rem >> 4, q = rem & 15;
        int gi = i0 - 1 + r, gj = j0 - 1 + p;
        f16x8 v = {0, 0, 0, 0, 0, 0, 0, 0};
        if (((unsigned)gi < 256u) && ((unsigned)gj < 256u))
            v = *(const f16x8*)&in[(((size_t)b * 256 + gi) * 256 + gj) * 128 + q * 8];
        *(f16x8*)&Al[(r * 18 + p) * 136 + q * 8] = v;
    }
    __syncthreads();

    const int lane = tid & 63, wid = tid >> 6;      // wave = one image row (m-tile)
    const int l16 = lane & 15, quad = lane >> 4;
    f32x4 acc = {};
    const int DR[5] = {1, 0, 2, 1, 1}, DP[5] = {1, 1, 1, 0, 2};

#pragma unroll
    for (int ks = 0; ks < 20; ++ks) {
        const int tap = ks >> 2, kc = ks & 3;
        const int koff = kc * 32 + quad * 8;
        f16x8 bf = *(const f16x8*)&W4g[(size_t)(tap * 16 + l16) * 128 + koff];
        f16x8 af = *(const f16x8*)&Al[((DR[tap] + wid) * 18 + DP[tap] + l16) * 136 + koff];
        acc = __builtin_amdgcn_mfma_f32_16x16x32_f16(af, bf, acc, 0, 0, 0);
    }

    if (l16 < 6) {
        const float bb = bias[l16];
        const int i = i0 + wid;
#pragma unroll
        for (int vi = 0; vi < 4; ++vi) {
            int jj = j0 + quad * 4 + vi;
            outp[(((size_t)b * 6 + l16) << 16) + i * 256 + jj] = acc[vi] + bb;
        }
    }
}

extern "C" void kernel_launch(void* const* d_in, const int* in_sizes, int n_in,
                              void* d_out, int out_size, void* d_ws, size_t ws_size,
                              hipStream_t stream) {
    const float* x  = (const float*)d_in[0];
    const float* w1 = (const float*)d_in[1];
    const float* b1 = (const float*)d_in[2];
    const float* w2 = (const float*)d_in[3];
    const float* b2 = (const float*)d_in[4];
    const float* w3 = (const float*)d_in[5];
    const float* b3 = (const float*)d_in[6];
    const float* w4 = (const float*)d_in[7];
    const float* b4 = (const float*)d_in[8];
    float* out = (float*)d_out;

    const size_t act = (size_t)BB * HH * WW * HIDC;      // 67108864 elems
    _Float16* A1 = (_Float16*)d_ws;
    _Float16* A2 = A1 + act;                             // exactly 268435456 B total

    prep<<<680, 256, 0, stream>>>(w2, w3, w4);
    l1_kernel<<<2048, 256, 0, stream>>>(x, w1, b1, A1);
    dim3 g(16, 64, 8), blk(256, 1, 1);
    gmid<2><<<g, blk, 0, stream>>>(A1, b2, A2);
    gmid<3><<<g, blk, 0, stream>>>(A2, b3, A1);
    g4<<<g, blk, 0, stream>>>(A1, b4, out);
}